// Round 2
// baseline (612.644 us; speedup 1.0000x reference)
//
#include <hip/hip_runtime.h>
#include <hip/hip_bf16.h>
#include <cstdint>

#define B_SZ 8192
#define NH 16
#define HD 256
#define FH 512
#define BR 64            // batch rows per ffn block

typedef __bf16 bf16x8 __attribute__((ext_vector_type(8)));
typedef float f32x4 __attribute__((ext_vector_type(4)));

#define VMCNT0() asm volatile("s_waitcnt vmcnt(0)" ::: "memory")
#define LGKM0()  asm volatile("s_waitcnt lgkmcnt(0)" ::: "memory")

// async global->LDS, 16 bytes per lane. lds base must be wave-uniform;
// lane i's data lands at lds_base + i*16.
__device__ __forceinline__ void lds_load16(const void* g, void* l) {
  __builtin_amdgcn_global_load_lds(
      (const __attribute__((address_space(1))) unsigned char*)g,
      (__attribute__((address_space(3))) unsigned char*)l, 16, 0, 0);
}

// ---------------- weight convert + transpose (all 3 weights in one launch):
// src fp32 [NH][K][N] -> dst bf16 [NH][N][K]
__global__ __launch_bounds__(256) void wcvt_kernel(const float* __restrict__ w1,
                                                   const float* __restrict__ w3,
                                                   const float* __restrict__ w2,
                                                   __bf16* __restrict__ w1t,
                                                   __bf16* __restrict__ w3t,
                                                   __bf16* __restrict__ w2t) {
  int bid = blockIdx.x;
  const float* src;
  __bf16* dst;
  int K, N;
  if (bid < 2048)      { src = w1; dst = w1t; K = 256; N = 512; }
  else if (bid < 4096) { src = w3; dst = w3t; K = 256; N = 512; bid -= 2048; }
  else                 { src = w2; dst = w2t; K = 512; N = 256; bid -= 4096; }
  const int tiles_n = N >> 5, tiles_k = K >> 5;
  const int per_head = tiles_n * tiles_k;
  const int head = bid / per_head;
  const int rem = bid - head * per_head;
  const int tk = rem / tiles_n;
  const int tn = rem - tk * tiles_n;
  __shared__ float tile[32][33];
  const float* s = src + ((size_t)head * K + tk * 32) * N + tn * 32;
  const int r = threadIdx.x >> 3;           // 0..31
  const int c4 = (threadIdx.x & 7) * 4;     // 0..28
  float4 v = *(const float4*)(s + (size_t)r * N + c4);
  tile[r][c4 + 0] = v.x; tile[r][c4 + 1] = v.y;
  tile[r][c4 + 2] = v.z; tile[r][c4 + 3] = v.w;
  __syncthreads();
  __bf16 o[4] __attribute__((aligned(8)));
  #pragma unroll
  for (int j = 0; j < 4; ++j) o[j] = (__bf16)tile[c4 + j][r];
  __bf16* d = dst + ((size_t)head * N + tn * 32 + r) * K + tk * 32 + c4;
  *(uint2*)d = *(uint2*)o;
}

// ---------------- prep: rmsnorm1 -> head-mix -> mask -> +x = p ; rmsnorm2 -> h
// 4 rows per block, 2048 blocks -> 8 blocks/CU (32 waves/CU) for latency cover.
#define PREP_R 4
__global__ __launch_bounds__(256) void prep_kernel(const float* __restrict__ x,
                                                   const float* __restrict__ n1w,
                                                   const float* __restrict__ n2w,
                                                   const float* __restrict__ mask,
                                                   __bf16* __restrict__ p_ws,
                                                   __bf16* __restrict__ h_ws) {
  const int t = threadIdx.x;
  const int g = t >> 4;     // head this thread produces
  const int li = t & 15;    // sub-block / source head index
  __shared__ float xs[16 * 260];
  __shared__ float rms1s[16];

  // invariant per-thread parameter caches
  float n1c[16], n2c[16], mc[16];
  #pragma unroll
  for (int j = 0; j < 4; ++j) {
    *(float4*)(n1c + j * 4) = *(const float4*)(n1w + g * 16 + j * 4);
    *(float4*)(n2c + j * 4) = *(const float4*)(n2w + li * 16 + j * 4);
    *(float4*)(mc + j * 4)  = *(const float4*)(mask + g * HD + li * 16 + j * 4);
  }

  for (int r = 0; r < PREP_R; ++r) {
    const int b = blockIdx.x * PREP_R + r;
    const float* xb = x + (size_t)b * (NH * HD);
    if (r) __syncthreads();   // xs free from previous row

    float xv[16];
    float ss = 0.f;
    #pragma unroll
    for (int j = 0; j < 4; ++j) {
      float4 v = *(const float4*)(xb + g * HD + li * 16 + j * 4);
      *(float4*)(xs + g * 260 + li * 16 + j * 4) = v;
      xv[j * 4 + 0] = v.x; xv[j * 4 + 1] = v.y;
      xv[j * 4 + 2] = v.z; xv[j * 4 + 3] = v.w;
      ss += v.x * v.x + v.y * v.y + v.z * v.z + v.w * v.w;
    }
    #pragma unroll
    for (int d = 1; d < 16; d <<= 1) ss += __shfl_xor(ss, d);
    if (li == 0) rms1s[g] = rsqrtf(ss * (1.f / 256.f) + 1e-6f);
    __syncthreads();

    const float r1 = rms1s[li];
    float pv[16];
    float ss2 = 0.f;
    #pragma unroll
    for (int j = 0; j < 4; ++j) {
      float4 sv = *(const float4*)(xs + li * 260 + g * 16 + j * 4);
      float s4[4] = {sv.x, sv.y, sv.z, sv.w};
      #pragma unroll
      for (int q = 0; q < 4; ++q) {
        const int k = j * 4 + q;
        const float mixed = s4[q] * r1 * n1c[k] * mc[k];
        const float p = mixed + xv[k];
        pv[k] = p;
        ss2 += p * p;
      }
    }
    #pragma unroll
    for (int d = 1; d < 16; d <<= 1) ss2 += __shfl_xor(ss2, d);
    const float r2 = rsqrtf(ss2 * (1.f / 256.f) + 1e-6f);

    __bf16 pb[16] __attribute__((aligned(16)));
    __bf16 hv[16] __attribute__((aligned(16)));
    #pragma unroll
    for (int k = 0; k < 16; ++k) {
      pb[k] = (__bf16)pv[k];
      hv[k] = (__bf16)(pv[k] * r2 * n2c[k]);
    }
    __bf16* pp = p_ws + ((size_t)g * B_SZ + b) * HD + li * 16;
    *(uint4*)(pp + 0) = *(uint4*)(pb + 0);
    *(uint4*)(pp + 8) = *(uint4*)(pb + 8);
    __bf16* hp = h_ws + ((size_t)g * B_SZ + b) * HD + li * 16;
    *(uint4*)(hp + 0) = *(uint4*)(hv + 0);
    *(uint4*)(hp + 8) = *(uint4*)(hv + 8);
  }
}

// ---------------- fused FFN v4: out = (silu(H W1) * (H W3)) W2 + p
// Weights are L2-resident (2 heads pinned per XCD, 1.5 MB < 4 MB L2), so all
// W1/W3/W2 A-fragments load DIRECTLY global->VGPR (no LDS staging, no DMA ring,
// no vmcnt bookkeeping — the compiler software-pipelines plain register loads).
// LDS = Hs(32K, broadcast-read B-fragments) + Sc(8K) = 40 KB -> 4 blocks/CU
// (4 waves/SIMD, 2x the v3 occupancy). Only sync: 2 raw s_barriers per hc
// around the Sc (silu output) exchange; no vmcnt drains anywhere in the loop.
__global__ __launch_bounds__(256, 4) void ffn_kernel(const __bf16* __restrict__ h_ws,
                                                     const __bf16* __restrict__ w1t,
                                                     const __bf16* __restrict__ w3t,
                                                     const __bf16* __restrict__ w2t,
                                                     const __bf16* __restrict__ p_ws,
                                                     float* __restrict__ out) {
  const int bid = blockIdx.x;
  const int head = bid & 15;            // head pinned to XCD bid%8 (2 heads/XCD)
  const int stripe = bid >> 4;          // 0..127
  const int r0 = stripe * BR;
  const int t = threadIdx.x;
  const int wv = t >> 6, lane = t & 63;
  const int mlane = lane & 15, quad = lane >> 4;

  __shared__ __bf16 __attribute__((aligned(16))) Hs[BR * HD];    // 32 KB [row][k], chunk c holds global c^(row&15)
  __shared__ __bf16 __attribute__((aligned(16))) Sc[BR * 64];    //  8 KB [row][hid], chunk c holds global c^(row&7)

  const __bf16* W1h = w1t + (size_t)head * FH * HD;
  const __bf16* W3h = w3t + (size_t)head * FH * HD;
  const __bf16* W2h = w2t + (size_t)head * HD * FH;

  // ---- prologue: DMA-stage Hs (8 loads/wave), swizzled chunk c^(row&15)
  const __bf16* Hb = h_ws + ((size_t)head * B_SZ + r0) * HD;
  {
    const int rloc = lane >> 5;       // 0/1
    const int ch = lane & 31;
    #pragma unroll
    for (int i = 0; i < 8; ++i) {
      const int row = wv * 16 + i * 2 + rloc;
      const int gch = ch ^ (row & 15);
      lds_load16(Hb + (size_t)row * HD + gch * 8, Hs + (wv * 16 + i * 2) * HD);
    }
  }
  VMCNT0();
  __builtin_amdgcn_s_barrier();     // Hs visible to all waves (read-only after)

  f32x4 oacc[4][4];
  #pragma unroll
  for (int mt = 0; mt < 4; ++mt)
    #pragma unroll
    for (int nt = 0; nt < 4; ++nt) oacc[mt][nt] = (f32x4){0.f, 0.f, 0.f, 0.f};

  for (int hc = 0; hc < 8; ++hc) {
    // ================= stage 1: g/v[16 hid rows this wave][64 batch], K=256 ====
    f32x4 g[4], v[4];
    #pragma unroll
    for (int nt = 0; nt < 4; ++nt) {
      g[nt] = (f32x4){0.f, 0.f, 0.f, 0.f};
      v[nt] = (f32x4){0.f, 0.f, 0.f, 0.f};
    }
    const int ar = hc * 64 + wv * 16 + mlane;     // global hid row this lane feeds
    #pragma unroll
    for (int kk = 0; kk < 4; ++kk) {
      #pragma unroll
      for (int ks = 0; ks < 2; ++ks) {
        const int koff = kk * 64 + (ks * 4 + quad) * 8;   // k element offset (16B aligned)
        bf16x8 a1 = *(const bf16x8*)(W1h + (size_t)ar * HD + koff);
        bf16x8 a3 = *(const bf16x8*)(W3h + (size_t)ar * HD + koff);
        const int gk = kk * 8 + ks * 4 + quad;            // 8-elem k-chunk (0..31)
        bf16x8 b[4];
        #pragma unroll
        for (int nt = 0; nt < 4; ++nt) {
          const int row = nt * 16 + mlane;
          b[nt] = *(const bf16x8*)(Hs + row * HD + (gk ^ (row & 15)) * 8);
        }
        __builtin_amdgcn_s_setprio(1);
        #pragma unroll
        for (int nt = 0; nt < 4; ++nt) {
          g[nt] = __builtin_amdgcn_mfma_f32_16x16x32_bf16(a1, b[nt], g[nt], 0, 0, 0);
          v[nt] = __builtin_amdgcn_mfma_f32_16x16x32_bf16(a3, b[nt], v[nt], 0, 0, 0);
        }
        __builtin_amdgcn_s_setprio(0);
      }
    }

    // ---- silu -> Sc  (wave wv owns hid-local cols wv*16..+15)
    #pragma unroll
    for (int nt = 0; nt < 4; ++nt) {
      const int row = nt * 16 + mlane;
      __bf16 sv[4] __attribute__((aligned(8)));
      #pragma unroll
      for (int r = 0; r < 4; ++r) {
        const float gg = g[nt][r];
        sv[r] = (__bf16)(gg / (1.f + __expf(-gg)) * v[nt][r]);
      }
      const int boff = wv * 32 + quad * 8;          // byte offset of hid-local in row
      const int ph = ((boff >> 4) ^ (row & 7));
      char* dst = (char*)Sc + row * 128 + ph * 16 + (boff & 15);
      *(uint2*)dst = *(uint2*)sv;
    }
    LGKM0();
    __builtin_amdgcn_s_barrier();   // BARRIER_A: Sc published

    // ================= stage 2: oacc += W2[:, hc*64..+64] * Sc =================
    #pragma unroll
    for (int ks = 0; ks < 2; ++ks) {
      bf16x8 a2[4], b2[4];
      #pragma unroll
      for (int mt = 0; mt < 4; ++mt) {
        const int orow = wv * 64 + mt * 16 + mlane;       // out-dim row
        a2[mt] = *(const bf16x8*)(W2h + (size_t)orow * FH + hc * 64 + ks * 32 + quad * 8);
      }
      #pragma unroll
      for (int nt = 0; nt < 4; ++nt) {
        const int row = nt * 16 + mlane;
        b2[nt] = *(const bf16x8*)(Sc + row * 64 + (((ks * 4 + quad) ^ (row & 7))) * 8);
      }
      __builtin_amdgcn_s_setprio(1);
      #pragma unroll
      for (int mt = 0; mt < 4; ++mt)
        #pragma unroll
        for (int nt = 0; nt < 4; ++nt)
          oacc[mt][nt] = __builtin_amdgcn_mfma_f32_16x16x32_bf16(a2[mt], b2[nt], oacc[mt][nt], 0, 0, 0);
      __builtin_amdgcn_s_setprio(0);
    }
    __builtin_amdgcn_s_barrier();   // BARRIER_B: all Sc reads retired before next silu
  }

  // ---- epilogue: out[b][head*256+oc] = oacc + p
  const __bf16* Pb = p_ws + ((size_t)head * B_SZ + r0) * HD;
  float* Ob = out + (size_t)r0 * (NH * HD) + head * HD;
  #pragma unroll
  for (int mt = 0; mt < 4; ++mt)
    #pragma unroll
    for (int nt = 0; nt < 4; ++nt) {
      const int row = nt * 16 + mlane;
      const int oc = wv * 64 + mt * 16 + quad * 4;
      __bf16 pv[4] __attribute__((aligned(8)));
      *(uint2*)pv = *(const uint2*)(Pb + (size_t)row * HD + oc);
      float4 o;
      o.x = oacc[mt][nt][0] + (float)pv[0];
      o.y = oacc[mt][nt][1] + (float)pv[1];
      o.z = oacc[mt][nt][2] + (float)pv[2];
      o.w = oacc[mt][nt][3] + (float)pv[3];
      *(float4*)(Ob + (size_t)row * (NH * HD) + oc) = o;
    }
}

extern "C" void kernel_launch(void* const* d_in, const int* in_sizes, int n_in,
                              void* d_out, int out_size, void* d_ws, size_t ws_size,
                              hipStream_t stream) {
  const float* x    = (const float*)d_in[0];
  const float* n1w  = (const float*)d_in[1];
  const float* n2w  = (const float*)d_in[2];
  const float* w1   = (const float*)d_in[3];
  const float* w3   = (const float*)d_in[4];
  const float* w2   = (const float*)d_in[5];
  const float* mask = (const float*)d_in[6];
  float* out = (float*)d_out;

  char* ws = (char*)d_ws;
  // ws layout (bytes):
  //   p_ws  bf16 [16][8192][256]  @ 0          (67108864)
  //   h_ws  bf16 [16][8192][256]  @ 67108864   (67108864)
  //   w1t   bf16 [16][512][256]   @ 134217728  ( 4194304)
  //   w3t   bf16 [16][512][256]   @ 138412032  ( 4194304)
  //   w2t   bf16 [16][256][512]   @ 142606336  ( 4194304)
  __bf16* p_ws = (__bf16*)(ws + 0);
  __bf16* h_ws = (__bf16*)(ws + 67108864);
  __bf16* w1t  = (__bf16*)(ws + 134217728);
  __bf16* w3t  = (__bf16*)(ws + 138412032);
  __bf16* w2t  = (__bf16*)(ws + 142606336);

  wcvt_kernel<<<6144, 256, 0, stream>>>(w1, w3, w2, w1t, w3t, w2t);
  prep_kernel<<<2048, 256, 0, stream>>>(x, n1w, n2w, mask, p_ws, h_ws);
  ffn_kernel<<<2048, 256, 0, stream>>>(h_ws, w1t, w3t, w2t, p_ws, out);
}

// Round 5
// 558.669 us; speedup vs baseline: 1.0966x; 1.0966x over previous
//
#include <hip/hip_runtime.h>
#include <hip/hip_bf16.h>
#include <cstdint>

#define B_SZ 8192
#define NH 16
#define HD 256
#define FH 512
#define BR 64            // batch rows per ffn block

typedef __bf16 bf16x8 __attribute__((ext_vector_type(8)));
typedef float f32x4 __attribute__((ext_vector_type(4)));

#define VMCNT(n) asm volatile("s_waitcnt vmcnt(" #n ")" ::: "memory")
#define LGKM0()  asm volatile("s_waitcnt lgkmcnt(0)" ::: "memory")
#define MEMFENCE() asm volatile("" ::: "memory")

// async global->LDS, 16 bytes per lane. lds base must be wave-uniform;
// lane i's data lands at lds_base + i*16.
__device__ __forceinline__ void lds_load16(const void* g, void* l) {
  __builtin_amdgcn_global_load_lds(
      (const __attribute__((address_space(1))) unsigned char*)g,
      (__attribute__((address_space(3))) unsigned char*)l, 16, 0, 0);
}

// ---------------- weight convert + transpose (round-1 verbatim):
// src fp32 [NH][K][N] -> dst bf16 [NH][N][K]
__global__ __launch_bounds__(256) void wcvt_kernel(const float* __restrict__ w1,
                                                   const float* __restrict__ w3,
                                                   const float* __restrict__ w2,
                                                   __bf16* __restrict__ w1t,
                                                   __bf16* __restrict__ w3t,
                                                   __bf16* __restrict__ w2t) {
  int bid = blockIdx.x;
  const float* src;
  __bf16* dst;
  int K, N;
  if (bid < 2048)      { src = w1; dst = w1t; K = 256; N = 512; }
  else if (bid < 4096) { src = w3; dst = w3t; K = 256; N = 512; bid -= 2048; }
  else                 { src = w2; dst = w2t; K = 512; N = 256; bid -= 4096; }
  const int tiles_n = N >> 5, tiles_k = K >> 5;
  const int per_head = tiles_n * tiles_k;
  const int head = bid / per_head;
  const int rem = bid - head * per_head;
  const int tk = rem / tiles_n;
  const int tn = rem - tk * tiles_n;
  __shared__ float tile[32][33];
  const float* s = src + ((size_t)head * K + tk * 32) * N + tn * 32;
  const int r = threadIdx.x >> 3;           // 0..31
  const int c4 = (threadIdx.x & 7) * 4;     // 0..28
  float4 v = *(const float4*)(s + (size_t)r * N + c4);
  tile[r][c4 + 0] = v.x; tile[r][c4 + 1] = v.y;
  tile[r][c4 + 2] = v.z; tile[r][c4 + 3] = v.w;
  __syncthreads();
  __bf16 o[4] __attribute__((aligned(8)));
  #pragma unroll
  for (int j = 0; j < 4; ++j) o[j] = (__bf16)tile[c4 + j][r];
  __bf16* d = dst + ((size_t)head * N + tn * 32 + r) * K + tk * 32 + c4;
  *(uint2*)d = *(uint2*)o;
}

// ---------------- prep (wave-per-row rewrite): rmsnorm1 -> mix -> mask -> +x ;
// rmsnorm2. One WAVE per batch row, zero barriers, zero LDS.
// lane l = (head i = l>>2, quarter c = l&3) owns output dims [c*64, c*64+64)
// of head i (i.e. source heads j = c*4..c*4+3, 16 dims each).
__global__ __launch_bounds__(256) void prep_kernel(const float* __restrict__ x,
                                                   const float* __restrict__ n1w,
                                                   const float* __restrict__ n2w,
                                                   const float* __restrict__ mask,
                                                   __bf16* __restrict__ p_ws,
                                                   __bf16* __restrict__ h_ws) {
  const int t = threadIdx.x;
  const int wv = t >> 6, l = t & 63;
  const int b = blockIdx.x * 4 + wv;
  const int i = l >> 2;            // produced head
  const int c = l & 3;             // quarter (source-head group c*4..c*4+3)
  const float* xb = x + (size_t)b * (NH * HD);

  // phase 1: own x slice + rms1 partial
  float a[64];                     // x_own, later becomes p
  float ss = 0.f;
  #pragma unroll
  for (int q = 0; q < 16; ++q) {
    float4 v = *(const float4*)(xb + i * HD + c * 64 + q * 4);
    a[q * 4 + 0] = v.x; a[q * 4 + 1] = v.y;
    a[q * 4 + 2] = v.z; a[q * 4 + 3] = v.w;
    ss += v.x * v.x + v.y * v.y + v.z * v.z + v.w * v.w;
  }
  ss += __shfl_xor(ss, 1);
  ss += __shfl_xor(ss, 2);         // quad of head i now holds full sum
  const float r1own = rsqrtf(ss * (1.f / 256.f) + 1e-6f);

  float n1c[16];
  #pragma unroll
  for (int q = 0; q < 4; ++q)
    *(float4*)(n1c + q * 4) = *(const float4*)(n1w + i * 16 + q * 4);

  // phase 2: mixed = x[b][j][i*16+k] * r1[j] * n1w[i*16+k] * mask[i][j*16+k]
  //          p = mixed + x_own ; accumulate rms2
  float ss2 = 0.f;
  #pragma unroll
  for (int jj = 0; jj < 4; ++jj) {
    const int j = c * 4 + jj;      // source head
    const float r1j = __shfl(r1own, j * 4);
    float xsrc[16], mk[16];
    #pragma unroll
    for (int q = 0; q < 4; ++q) {
      *(float4*)(xsrc + q * 4) = *(const float4*)(xb + j * HD + i * 16 + q * 4);
      *(float4*)(mk + q * 4)   = *(const float4*)(mask + i * HD + j * 16 + q * 4);
    }
    #pragma unroll
    for (int k = 0; k < 16; ++k) {
      const float p = xsrc[k] * r1j * n1c[k] * mk[k] + a[jj * 16 + k];
      a[jj * 16 + k] = p;
      ss2 += p * p;
    }
  }
  ss2 += __shfl_xor(ss2, 1);
  ss2 += __shfl_xor(ss2, 2);
  const float r2 = rsqrtf(ss2 * (1.f / 256.f) + 1e-6f);

  // phase 3: pack + store (64 contiguous bf16 per lane per buffer)
  __bf16* pp = p_ws + ((size_t)i * B_SZ + b) * HD + c * 64;
  __bf16* hp = h_ws + ((size_t)i * B_SZ + b) * HD + c * 64;
  #pragma unroll
  for (int jj = 0; jj < 4; ++jj) {
    float n2c[16];
    #pragma unroll
    for (int q = 0; q < 4; ++q)
      *(float4*)(n2c + q * 4) = *(const float4*)(n2w + (c * 4 + jj) * 16 + q * 4);
    __bf16 pb[16] __attribute__((aligned(16)));
    __bf16 hv[16] __attribute__((aligned(16)));
    #pragma unroll
    for (int k = 0; k < 16; ++k) {
      const float p = a[jj * 16 + k];
      pb[k] = (__bf16)p;
      hv[k] = (__bf16)(p * r2 * n2c[k]);
    }
    *(uint4*)(pp + jj * 16 + 0) = *(uint4*)(pb + 0);
    *(uint4*)(pp + jj * 16 + 8) = *(uint4*)(pb + 8);
    *(uint4*)(hp + jj * 16 + 0) = *(uint4*)(hv + 0);
    *(uint4*)(hp + jj * 16 + 8) = *(uint4*)(hv + 8);
  }
}

// ---------------- fused FFN (round-1 version, verbatim): counted-vmcnt ring.
// Per hc: 6 uniform stages of 4 global_load_lds/lane ping-pong across two
// 16KB Wbuf slots. All weight staging is wave-byte-private, so NO barriers
// guard Wbuf — only each wave's own s_waitcnt vmcnt(4). Cross-wave barriers:
// only the Sc publish and Sc WAR (2 raw s_barriers per hc).
__global__ __launch_bounds__(256, 2) void ffn_kernel(const __bf16* __restrict__ h_ws,
                                                     const __bf16* __restrict__ w1t,
                                                     const __bf16* __restrict__ w3t,
                                                     const __bf16* __restrict__ w2t,
                                                     const __bf16* __restrict__ p_ws,
                                                     float* __restrict__ out) {
  const int bid = blockIdx.x;
  const int head = bid & 15;            // head pinned to XCD bid%8 (2 heads/XCD)
  const int stripe = bid >> 4;          // 0..127
  const int r0 = stripe * BR;
  const int t = threadIdx.x;
  const int wv = t >> 6, lane = t & 63;
  const int mlane = lane & 15, quad = lane >> 4;

  __shared__ __bf16 __attribute__((aligned(16))) Hs[BR * HD];    // 32 KB [row][k], chunk c holds global c^(row&15)
  __shared__ __bf16 __attribute__((aligned(16))) Wbuf[16384];    // 32 KB = 2 slots x 16 KB (ring)
  __shared__ __bf16 __attribute__((aligned(16))) Sc[BR * 64];    //  8 KB [row][hid], chunk c holds global c^(row&7)

  const __bf16* W1h = w1t + (size_t)head * FH * HD;
  const __bf16* W3h = w3t + (size_t)head * FH * HD;
  const __bf16* W2h = w2t + (size_t)head * HD * FH;

  // ---- stage issue helpers (4 DMA loads/lane each; all wave-byte-private) ----
  auto stage1_issue = [&](__bf16* Ws, int hc, int kk) {
    const int rl = lane >> 3, c = lane & 7, gch = c ^ rl;
    #pragma unroll
    for (int i = 0; i < 2; ++i) {
      const int rb = wv * 16 + i * 8;
      const size_t go = (size_t)(hc * 64 + rb + rl) * HD + kk * 64 + gch * 8;
      lds_load16(W1h + go, Ws + rb * 64);
      lds_load16(W3h + go, Ws + 4096 + rb * 64);
    }
  };
  auto stage2_issue = [&](__bf16* Ws, int hc, int ks) {
    const int rl = lane >> 2, c = lane & 3, gch = c ^ (rl & 3);
    #pragma unroll
    for (int i = 0; i < 4; ++i) {
      const int rb = wv * 64 + i * 16;
      lds_load16(W2h + (size_t)(rb + rl) * FH + hc * 64 + ks * 32 + gch * 8,
                 Ws + (i >> 1) * 4096 + wv * 1024 + (i & 1) * 512);
    }
  };

  // ---- prologue: stage Hs (8 loads/wave), then prefetch s1k0/s1k1 of hc=0
  const __bf16* Hb = h_ws + ((size_t)head * B_SZ + r0) * HD;
  {
    const int rloc = lane >> 5;       // 0/1
    const int ch = lane & 31;
    #pragma unroll
    for (int i = 0; i < 8; ++i) {
      const int row = wv * 16 + i * 2 + rloc;
      const int gch = ch ^ (row & 15);
      lds_load16(Hb + (size_t)row * HD + gch * 8, Hs + (wv * 16 + i * 2) * HD);
    }
  }
  MEMFENCE();                       // keep Hs DMAs ordered before prefetches
  stage1_issue(Wbuf, 0, 0);
  stage1_issue(Wbuf + 8192, 0, 1);
  VMCNT(8);                         // own 8 Hs loads done (8 prefetches in flight)
  __builtin_amdgcn_s_barrier();     // Hs visible to all waves (read-only after)

  f32x4 oacc[4][4];
  #pragma unroll
  for (int mt = 0; mt < 4; ++mt)
    #pragma unroll
    for (int nt = 0; nt < 4; ++nt) oacc[mt][nt] = (f32x4){0.f, 0.f, 0.f, 0.f};

  for (int hc = 0; hc < 8; ++hc) {
    // ================= stage 1: g/v[64 hid chunk][64 rows], K=256 =================
    f32x4 g[4], v[4];
    #pragma unroll
    for (int nt = 0; nt < 4; ++nt) {
      g[nt] = (f32x4){0.f, 0.f, 0.f, 0.f};
      v[nt] = (f32x4){0.f, 0.f, 0.f, 0.f};
    }
    #pragma unroll
    for (int kk = 0; kk < 4; ++kk) {
      __bf16* Ws = Wbuf + (kk & 1) * 8192;
      VMCNT(4);                     // own slot loads done; next stage in flight
      #pragma unroll
      for (int ks = 0; ks < 2; ++ks) {
        const int ar = wv * 16 + mlane;            // wave-private hid row
        const int ach = (ks * 4 + quad) ^ (ar & 7);
        bf16x8 a1 = *(const bf16x8*)(Ws + ar * 64 + ach * 8);
        bf16x8 a3 = *(const bf16x8*)(Ws + 4096 + ar * 64 + ach * 8);
        const int gk = kk * 8 + ks * 4 + quad;     // global 8-elem k-chunk
        bf16x8 b[4];
        #pragma unroll
        for (int nt = 0; nt < 4; ++nt) {
          const int row = nt * 16 + mlane;
          b[nt] = *(const bf16x8*)(Hs + row * HD + (gk ^ (row & 15)) * 8);
        }
        if (ks == 1) {
          LGKM0();                  // this wave's slot reads retired -> safe to overwrite
          if (kk < 2) stage1_issue(Ws, hc, kk + 2);
          else        stage2_issue(Ws, hc, kk - 2);
        }
        __builtin_amdgcn_s_setprio(1);
        #pragma unroll
        for (int nt = 0; nt < 4; ++nt) {
          g[nt] = __builtin_amdgcn_mfma_f32_16x16x32_bf16(a1, b[nt], g[nt], 0, 0, 0);
          v[nt] = __builtin_amdgcn_mfma_f32_16x16x32_bf16(a3, b[nt], v[nt], 0, 0, 0);
        }
        __builtin_amdgcn_s_setprio(0);
      }
    }

    // ---- silu -> Sc
    #pragma unroll
    for (int nt = 0; nt < 4; ++nt) {
      const int row = nt * 16 + mlane;
      __bf16 sv[4] __attribute__((aligned(8)));
      #pragma unroll
      for (int r = 0; r < 4; ++r) {
        const float gg = g[nt][r];
        sv[r] = (__bf16)(gg / (1.f + __expf(-gg)) * v[nt][r]);
      }
      const int boff = wv * 32 + quad * 8;          // byte offset of hid-local in row
      const int ph = ((boff >> 4) ^ (row & 7));
      char* dst = (char*)Sc + row * 128 + ph * 16 + (boff & 15);
      *(uint2*)dst = *(uint2*)sv;
    }
    LGKM0();
    __builtin_amdgcn_s_barrier();   // BARRIER_A: Sc published (counted vmcnt untouched)

    // ================= stage 2: oacc += W2[:, hc*64..+64] * Sc =================
    const int hcn = (hc + 1) & 7;   // hc=7 issues dummy hc=0 prefetches (keeps vmcnt math uniform)
    #pragma unroll
    for (int ks = 0; ks < 2; ++ks) {
      __bf16* Ws = Wbuf + (ks & 1) * 8192;
      VMCNT(4);                     // own W2 chunk done; other stage in flight
      bf16x8 a2[4], b2[4];
      #pragma unroll
      for (int mt = 0; mt < 4; ++mt)
        a2[mt] = *(const bf16x8*)(Ws + (mt >> 1) * 4096 + wv * 1024 + (mt & 1) * 512
                                  + mlane * 32 + ((quad ^ (mlane & 3))) * 8);
      #pragma unroll
      for (int nt = 0; nt < 4; ++nt) {
        const int row = nt * 16 + mlane;
        b2[nt] = *(const bf16x8*)(Sc + row * 64 + (((ks * 4 + quad) ^ (row & 7))) * 8);
      }
      LGKM0();                      // Sc + slot reads retired
      stage1_issue(Ws, hcn, ks);    // prefetch next hc's s1k0/s1k1
      if (ks == 1) __builtin_amdgcn_s_barrier();  // BARRIER_B: Sc WAR before next silu
      __builtin_amdgcn_s_setprio(1);
      #pragma unroll
      for (int mt = 0; mt < 4; ++mt)
        #pragma unroll
        for (int nt = 0; nt < 4; ++nt)
          oacc[mt][nt] = __builtin_amdgcn_mfma_f32_16x16x32_bf16(a2[mt], b2[nt], oacc[mt][nt], 0, 0, 0);
      __builtin_amdgcn_s_setprio(0);
    }
  }

  VMCNT(0);   // drain dummy prefetches: no DMA may outlive this block's LDS

  // ---- epilogue: out[b][head*256+oc] = oacc + p
  const __bf16* Pb = p_ws + ((size_t)head * B_SZ + r0) * HD;
  float* Ob = out + (size_t)r0 * (NH * HD) + head * HD;
  #pragma unroll
  for (int mt = 0; mt < 4; ++mt)
    #pragma unroll
    for (int nt = 0; nt < 4; ++nt) {
      const int row = nt * 16 + mlane;
      const int oc = wv * 64 + mt * 16 + quad * 4;
      __bf16 pv[4] __attribute__((aligned(8)));
      *(uint2*)pv = *(const uint2*)(Pb + (size_t)row * HD + oc);
      float4 o;
      o.x = oacc[mt][nt][0] + (float)pv[0];
      o.y = oacc[mt][nt][1] + (float)pv[1];
      o.z = oacc[mt][nt][2] + (float)pv[2];
      o.w = oacc[mt][nt][3] + (float)pv[3];
      *(float4*)(Ob + (size_t)row * (NH * HD) + oc) = o;
    }
}

extern "C" void kernel_launch(void* const* d_in, const int* in_sizes, int n_in,
                              void* d_out, int out_size, void* d_ws, size_t ws_size,
                              hipStream_t stream) {
  const float* x    = (const float*)d_in[0];
  const float* n1w  = (const float*)d_in[1];
  const float* n2w  = (const float*)d_in[2];
  const float* w1   = (const float*)d_in[3];
  const float* w3   = (const float*)d_in[4];
  const float* w2   = (const float*)d_in[5];
  const float* mask = (const float*)d_in[6];
  float* out = (float*)d_out;

  char* ws = (char*)d_ws;
  // ws layout (bytes):
  //   p_ws  bf16 [16][8192][256]  @ 0          (67108864)
  //   h_ws  bf16 [16][8192][256]  @ 67108864   (67108864)
  //   w1t   bf16 [16][512][256]   @ 134217728  ( 4194304)
  //   w3t   bf16 [16][512][256]   @ 138412032  ( 4194304)
  //   w2t   bf16 [16][256][512]   @ 142606336  ( 4194304)
  __bf16* p_ws = (__bf16*)(ws + 0);
  __bf16* h_ws = (__bf16*)(ws + 67108864);
  __bf16* w1t  = (__bf16*)(ws + 134217728);
  __bf16* w3t  = (__bf16*)(ws + 138412032);
  __bf16* w2t  = (__bf16*)(ws + 142606336);

  wcvt_kernel<<<6144, 256, 0, stream>>>(w1, w3, w2, w1t, w3t, w2t);
  prep_kernel<<<2048, 256, 0, stream>>>(x, n1w, n2w, mask, p_ws, h_ws);
  ffn_kernel<<<2048, 256, 0, stream>>>(h_ws, w1t, w3t, w2t, p_ws, out);
}

// Round 6
// 414.766 us; speedup vs baseline: 1.4771x; 1.3469x over previous
//
#include <hip/hip_runtime.h>
#include <hip/hip_bf16.h>
#include <cstdint>

#define B_SZ 8192
#define NH 16
#define HD 256
#define FH 512
#define BR 64            // batch rows per ffn block

typedef __bf16 bf16x8 __attribute__((ext_vector_type(8)));
typedef float f32x4 __attribute__((ext_vector_type(4)));

#define VMCNT(n) asm volatile("s_waitcnt vmcnt(" #n ")" ::: "memory")
#define LGKM0()  asm volatile("s_waitcnt lgkmcnt(0)" ::: "memory")
#define MEMFENCE() asm volatile("" ::: "memory")

// async global->LDS, 16 bytes per lane. lds base must be wave-uniform;
// lane i's data lands at lds_base + i*16.
__device__ __forceinline__ void lds_load16(const void* g, void* l) {
  __builtin_amdgcn_global_load_lds(
      (const __attribute__((address_space(1))) unsigned char*)g,
      (__attribute__((address_space(3))) unsigned char*)l, 16, 0, 0);
}

// ---------------- weight convert + transpose (round-1 verbatim):
// src fp32 [NH][K][N] -> dst bf16 [NH][N][K]
__global__ __launch_bounds__(256) void wcvt_kernel(const float* __restrict__ w1,
                                                   const float* __restrict__ w3,
                                                   const float* __restrict__ w2,
                                                   __bf16* __restrict__ w1t,
                                                   __bf16* __restrict__ w3t,
                                                   __bf16* __restrict__ w2t) {
  int bid = blockIdx.x;
  const float* src;
  __bf16* dst;
  int K, N;
  if (bid < 2048)      { src = w1; dst = w1t; K = 256; N = 512; }
  else if (bid < 4096) { src = w3; dst = w3t; K = 256; N = 512; bid -= 2048; }
  else                 { src = w2; dst = w2t; K = 512; N = 256; bid -= 4096; }
  const int tiles_n = N >> 5, tiles_k = K >> 5;
  const int per_head = tiles_n * tiles_k;
  const int head = bid / per_head;
  const int rem = bid - head * per_head;
  const int tk = rem / tiles_n;
  const int tn = rem - tk * tiles_n;
  __shared__ float tile[32][33];
  const float* s = src + ((size_t)head * K + tk * 32) * N + tn * 32;
  const int r = threadIdx.x >> 3;           // 0..31
  const int c4 = (threadIdx.x & 7) * 4;     // 0..28
  float4 v = *(const float4*)(s + (size_t)r * N + c4);
  tile[r][c4 + 0] = v.x; tile[r][c4 + 1] = v.y;
  tile[r][c4 + 2] = v.z; tile[r][c4 + 3] = v.w;
  __syncthreads();
  __bf16 o[4] __attribute__((aligned(8)));
  #pragma unroll
  for (int j = 0; j < 4; ++j) o[j] = (__bf16)tile[c4 + j][r];
  __bf16* d = dst + ((size_t)head * N + tn * 32 + r) * K + tk * 32 + c4;
  *(uint2*)d = *(uint2*)o;
}

// ---------------- prep v3 (coalesced): one block per batch row.
// Thread t owns float4 chunks m = t + 256q (q=0..3) of the 4096-float row —
// loads and stores are fully coalesced (4KB contiguous per load instruction,
// 512B contiguous per store instruction). For fixed (wave w, q) all 64 lanes
// hold head i = w + 4q, so rms1/rms2 are pure wave shfl-reductions. Head-mix
// transpose via 16KB LDS tile, XOR-swizzled (phys = m ^ ((m>>6)&7)) so both
// write and transposed read sit at ds_*_b128's structural minimum aliasing.
// ONE __syncthreads per block.
__global__ __launch_bounds__(256) void prep_kernel(const float* __restrict__ x,
                                                   const float* __restrict__ n1w,
                                                   const float* __restrict__ n2w,
                                                   const float* __restrict__ mask,
                                                   __bf16* __restrict__ p_ws,
                                                   __bf16* __restrict__ h_ws) {
  const int t = threadIdx.x;
  const int b = blockIdx.x;
  const int w = t >> 6;            // wave 0..3
  const int l = t & 63;            // lane
  __shared__ float4 xs[1024];      // 16 KB, swizzled storage of the row
  __shared__ float rms1s[16];

  const float4* xb4 = (const float4*)(x + (size_t)b * (NH * HD));

  // ---- phase 1: coalesced load + per-head sumsq (head of chunk q is w+4q)
  float4 xq[4];
  float ssq[4];
  #pragma unroll
  for (int q = 0; q < 4; ++q) {
    const int m = t + 256 * q;
    float4 v = xb4[m];
    xq[q] = v;
    ssq[q] = v.x * v.x + v.y * v.y + v.z * v.z + v.w * v.w;
    xs[m ^ ((m >> 6) & 7)] = v;    // swizzled stash for the transpose
  }
  #pragma unroll
  for (int d = 1; d < 64; d <<= 1) {
    #pragma unroll
    for (int q = 0; q < 4; ++q) ssq[q] += __shfl_xor(ssq[q], d);
  }
  if (l == 0) {
    #pragma unroll
    for (int q = 0; q < 4; ++q)
      rms1s[w + 4 * q] = rsqrtf(ssq[q] * (1.f / 256.f) + 1e-6f);
  }
  __syncthreads();                 // xs + rms1s published (only barrier)

  // ---- phase 2: transpose-read + mix + mask + residual; rms2 per head (wave-local)
  // output chunk m = t+256q: head i = m>>6, c4 = m&63, source head j = c4>>2,
  // sub-quarter u = c4&3. mixed dims d = j*16 + u*4 + e come from
  // x[b][j][i*16 + u*4 + e] * r1[j] * n1w[i*16+u*4+e] * mask[i][d].
  float4 pq[4];
  float ssq2[4];
  #pragma unroll
  for (int q = 0; q < 4; ++q) {
    const int m = t + 256 * q;
    const int i = m >> 6;
    const int c4 = m & 63;
    const int j = c4 >> 2;
    const int u = c4 & 3;
    const int src = j * 64 + i * 4 + u;          // src>>6 == j
    float4 sv = xs[src ^ (j & 7)];
    const float r1 = rms1s[j];
    float4 n1 = *(const float4*)(n1w + i * 16 + u * 4);
    float4 mk = *(const float4*)(mask + i * HD + j * 16 + u * 4);
    float4 p;
    p.x = sv.x * r1 * n1.x * mk.x + xq[q].x;
    p.y = sv.y * r1 * n1.y * mk.y + xq[q].y;
    p.z = sv.z * r1 * n1.z * mk.z + xq[q].z;
    p.w = sv.w * r1 * n1.w * mk.w + xq[q].w;
    pq[q] = p;
    ssq2[q] = p.x * p.x + p.y * p.y + p.z * p.z + p.w * p.w;
  }
  #pragma unroll
  for (int d = 1; d < 64; d <<= 1) {
    #pragma unroll
    for (int q = 0; q < 4; ++q) ssq2[q] += __shfl_xor(ssq2[q], d);
  }

  // ---- phase 3: pack + coalesced store (512B contiguous per wave per instr)
  #pragma unroll
  for (int q = 0; q < 4; ++q) {
    const int m = t + 256 * q;
    const int i = m >> 6;
    const int c4 = m & 63;
    const float r2 = rsqrtf(ssq2[q] * (1.f / 256.f) + 1e-6f);
    float4 n2 = *(const float4*)(n2w + c4 * 4);
    __bf16 pb[4] __attribute__((aligned(8)));
    __bf16 hv[4] __attribute__((aligned(8)));
    pb[0] = (__bf16)pq[q].x; hv[0] = (__bf16)(pq[q].x * r2 * n2.x);
    pb[1] = (__bf16)pq[q].y; hv[1] = (__bf16)(pq[q].y * r2 * n2.y);
    pb[2] = (__bf16)pq[q].z; hv[2] = (__bf16)(pq[q].z * r2 * n2.z);
    pb[3] = (__bf16)pq[q].w; hv[3] = (__bf16)(pq[q].w * r2 * n2.w);
    const size_t off = ((size_t)i * B_SZ + b) * HD + c4 * 4;
    *(uint2*)(p_ws + off) = *(uint2*)pb;
    *(uint2*)(h_ws + off) = *(uint2*)hv;
  }
}

// ---------------- fused FFN (round-1 version, verbatim): counted-vmcnt ring.
// Per hc: 6 uniform stages of 4 global_load_lds/lane ping-pong across two
// 16KB Wbuf slots. All weight staging is wave-byte-private, so NO barriers
// guard Wbuf — only each wave's own s_waitcnt vmcnt(4). Cross-wave barriers:
// only the Sc publish and Sc WAR (2 raw s_barriers per hc).
__global__ __launch_bounds__(256, 2) void ffn_kernel(const __bf16* __restrict__ h_ws,
                                                     const __bf16* __restrict__ w1t,
                                                     const __bf16* __restrict__ w3t,
                                                     const __bf16* __restrict__ w2t,
                                                     const __bf16* __restrict__ p_ws,
                                                     float* __restrict__ out) {
  const int bid = blockIdx.x;
  const int head = bid & 15;            // head pinned to XCD bid%8 (2 heads/XCD)
  const int stripe = bid >> 4;          // 0..127
  const int r0 = stripe * BR;
  const int t = threadIdx.x;
  const int wv = t >> 6, lane = t & 63;
  const int mlane = lane & 15, quad = lane >> 4;

  __shared__ __bf16 __attribute__((aligned(16))) Hs[BR * HD];    // 32 KB [row][k], chunk c holds global c^(row&15)
  __shared__ __bf16 __attribute__((aligned(16))) Wbuf[16384];    // 32 KB = 2 slots x 16 KB (ring)
  __shared__ __bf16 __attribute__((aligned(16))) Sc[BR * 64];    //  8 KB [row][hid], chunk c holds global c^(row&7)

  const __bf16* W1h = w1t + (size_t)head * FH * HD;
  const __bf16* W3h = w3t + (size_t)head * FH * HD;
  const __bf16* W2h = w2t + (size_t)head * HD * FH;

  // ---- stage issue helpers (4 DMA loads/lane each; all wave-byte-private) ----
  auto stage1_issue = [&](__bf16* Ws, int hc, int kk) {
    const int rl = lane >> 3, c = lane & 7, gch = c ^ rl;
    #pragma unroll
    for (int i = 0; i < 2; ++i) {
      const int rb = wv * 16 + i * 8;
      const size_t go = (size_t)(hc * 64 + rb + rl) * HD + kk * 64 + gch * 8;
      lds_load16(W1h + go, Ws + rb * 64);
      lds_load16(W3h + go, Ws + 4096 + rb * 64);
    }
  };
  auto stage2_issue = [&](__bf16* Ws, int hc, int ks) {
    const int rl = lane >> 2, c = lane & 3, gch = c ^ (rl & 3);
    #pragma unroll
    for (int i = 0; i < 4; ++i) {
      const int rb = wv * 64 + i * 16;
      lds_load16(W2h + (size_t)(rb + rl) * FH + hc * 64 + ks * 32 + gch * 8,
                 Ws + (i >> 1) * 4096 + wv * 1024 + (i & 1) * 512);
    }
  };

  // ---- prologue: stage Hs (8 loads/wave), then prefetch s1k0/s1k1 of hc=0
  const __bf16* Hb = h_ws + ((size_t)head * B_SZ + r0) * HD;
  {
    const int rloc = lane >> 5;       // 0/1
    const int ch = lane & 31;
    #pragma unroll
    for (int i = 0; i < 8; ++i) {
      const int row = wv * 16 + i * 2 + rloc;
      const int gch = ch ^ (row & 15);
      lds_load16(Hb + (size_t)row * HD + gch * 8, Hs + (wv * 16 + i * 2) * HD);
    }
  }
  MEMFENCE();                       // keep Hs DMAs ordered before prefetches
  stage1_issue(Wbuf, 0, 0);
  stage1_issue(Wbuf + 8192, 0, 1);
  VMCNT(8);                         // own 8 Hs loads done (8 prefetches in flight)
  __builtin_amdgcn_s_barrier();     // Hs visible to all waves (read-only after)

  f32x4 oacc[4][4];
  #pragma unroll
  for (int mt = 0; mt < 4; ++mt)
    #pragma unroll
    for (int nt = 0; nt < 4; ++nt) oacc[mt][nt] = (f32x4){0.f, 0.f, 0.f, 0.f};

  for (int hc = 0; hc < 8; ++hc) {
    // ================= stage 1: g/v[64 hid chunk][64 rows], K=256 =================
    f32x4 g[4], v[4];
    #pragma unroll
    for (int nt = 0; nt < 4; ++nt) {
      g[nt] = (f32x4){0.f, 0.f, 0.f, 0.f};
      v[nt] = (f32x4){0.f, 0.f, 0.f, 0.f};
    }
    #pragma unroll
    for (int kk = 0; kk < 4; ++kk) {
      __bf16* Ws = Wbuf + (kk & 1) * 8192;
      VMCNT(4);                     // own slot loads done; next stage in flight
      #pragma unroll
      for (int ks = 0; ks < 2; ++ks) {
        const int ar = wv * 16 + mlane;            // wave-private hid row
        const int ach = (ks * 4 + quad) ^ (ar & 7);
        bf16x8 a1 = *(const bf16x8*)(Ws + ar * 64 + ach * 8);
        bf16x8 a3 = *(const bf16x8*)(Ws + 4096 + ar * 64 + ach * 8);
        const int gk = kk * 8 + ks * 4 + quad;     // global 8-elem k-chunk
        bf16x8 b[4];
        #pragma unroll
        for (int nt = 0; nt < 4; ++nt) {
          const int row = nt * 16 + mlane;
          b[nt] = *(const bf16x8*)(Hs + row * HD + (gk ^ (row & 15)) * 8);
        }
        if (ks == 1) {
          LGKM0();                  // this wave's slot reads retired -> safe to overwrite
          if (kk < 2) stage1_issue(Ws, hc, kk + 2);
          else        stage2_issue(Ws, hc, kk - 2);
        }
        __builtin_amdgcn_s_setprio(1);
        #pragma unroll
        for (int nt = 0; nt < 4; ++nt) {
          g[nt] = __builtin_amdgcn_mfma_f32_16x16x32_bf16(a1, b[nt], g[nt], 0, 0, 0);
          v[nt] = __builtin_amdgcn_mfma_f32_16x16x32_bf16(a3, b[nt], v[nt], 0, 0, 0);
        }
        __builtin_amdgcn_s_setprio(0);
      }
    }

    // ---- silu -> Sc
    #pragma unroll
    for (int nt = 0; nt < 4; ++nt) {
      const int row = nt * 16 + mlane;
      __bf16 sv[4] __attribute__((aligned(8)));
      #pragma unroll
      for (int r = 0; r < 4; ++r) {
        const float gg = g[nt][r];
        sv[r] = (__bf16)(gg / (1.f + __expf(-gg)) * v[nt][r]);
      }
      const int boff = wv * 32 + quad * 8;          // byte offset of hid-local in row
      const int ph = ((boff >> 4) ^ (row & 7));
      char* dst = (char*)Sc + row * 128 + ph * 16 + (boff & 15);
      *(uint2*)dst = *(uint2*)sv;
    }
    LGKM0();
    __builtin_amdgcn_s_barrier();   // BARRIER_A: Sc published (counted vmcnt untouched)

    // ================= stage 2: oacc += W2[:, hc*64..+64] * Sc =================
    const int hcn = (hc + 1) & 7;   // hc=7 issues dummy hc=0 prefetches (keeps vmcnt math uniform)
    #pragma unroll
    for (int ks = 0; ks < 2; ++ks) {
      __bf16* Ws = Wbuf + (ks & 1) * 8192;
      VMCNT(4);                     // own W2 chunk done; other stage in flight
      bf16x8 a2[4], b2[4];
      #pragma unroll
      for (int mt = 0; mt < 4; ++mt)
        a2[mt] = *(const bf16x8*)(Ws + (mt >> 1) * 4096 + wv * 1024 + (mt & 1) * 512
                                  + mlane * 32 + ((quad ^ (mlane & 3))) * 8);
      #pragma unroll
      for (int nt = 0; nt < 4; ++nt) {
        const int row = nt * 16 + mlane;
        b2[nt] = *(const bf16x8*)(Sc + row * 64 + (((ks * 4 + quad) ^ (row & 7))) * 8);
      }
      LGKM0();                      // Sc + slot reads retired
      stage1_issue(Ws, hcn, ks);    // prefetch next hc's s1k0/s1k1
      if (ks == 1) __builtin_amdgcn_s_barrier();  // BARRIER_B: Sc WAR before next silu
      __builtin_amdgcn_s_setprio(1);
      #pragma unroll
      for (int mt = 0; mt < 4; ++mt)
        #pragma unroll
        for (int nt = 0; nt < 4; ++nt)
          oacc[mt][nt] = __builtin_amdgcn_mfma_f32_16x16x32_bf16(a2[mt], b2[nt], oacc[mt][nt], 0, 0, 0);
      __builtin_amdgcn_s_setprio(0);
    }
  }

  VMCNT(0);   // drain dummy prefetches: no DMA may outlive this block's LDS

  // ---- epilogue: out[b][head*256+oc] = oacc + p
  const __bf16* Pb = p_ws + ((size_t)head * B_SZ + r0) * HD;
  float* Ob = out + (size_t)r0 * (NH * HD) + head * HD;
  #pragma unroll
  for (int mt = 0; mt < 4; ++mt)
    #pragma unroll
    for (int nt = 0; nt < 4; ++nt) {
      const int row = nt * 16 + mlane;
      const int oc = wv * 64 + mt * 16 + quad * 4;
      __bf16 pv[4] __attribute__((aligned(8)));
      *(uint2*)pv = *(const uint2*)(Pb + (size_t)row * HD + oc);
      float4 o;
      o.x = oacc[mt][nt][0] + (float)pv[0];
      o.y = oacc[mt][nt][1] + (float)pv[1];
      o.z = oacc[mt][nt][2] + (float)pv[2];
      o.w = oacc[mt][nt][3] + (float)pv[3];
      *(float4*)(Ob + (size_t)row * (NH * HD) + oc) = o;
    }
}

extern "C" void kernel_launch(void* const* d_in, const int* in_sizes, int n_in,
                              void* d_out, int out_size, void* d_ws, size_t ws_size,
                              hipStream_t stream) {
  const float* x    = (const float*)d_in[0];
  const float* n1w  = (const float*)d_in[1];
  const float* n2w  = (const float*)d_in[2];
  const float* w1   = (const float*)d_in[3];
  const float* w3   = (const float*)d_in[4];
  const float* w2   = (const float*)d_in[5];
  const float* mask = (const float*)d_in[6];
  float* out = (float*)d_out;

  char* ws = (char*)d_ws;
  // ws layout (bytes):
  //   p_ws  bf16 [16][8192][256]  @ 0          (67108864)
  //   h_ws  bf16 [16][8192][256]  @ 67108864   (67108864)
  //   w1t   bf16 [16][512][256]   @ 134217728  ( 4194304)
  //   w3t   bf16 [16][512][256]   @ 138412032  ( 4194304)
  //   w2t   bf16 [16][256][512]   @ 142606336  ( 4194304)
  __bf16* p_ws = (__bf16*)(ws + 0);
  __bf16* h_ws = (__bf16*)(ws + 67108864);
  __bf16* w1t  = (__bf16*)(ws + 134217728);
  __bf16* w3t  = (__bf16*)(ws + 138412032);
  __bf16* w2t  = (__bf16*)(ws + 142606336);

  wcvt_kernel<<<6144, 256, 0, stream>>>(w1, w3, w2, w1t, w3t, w2t);
  prep_kernel<<<8192, 256, 0, stream>>>(x, n1w, n2w, mask, p_ws, h_ws);
  ffn_kernel<<<2048, 256, 0, stream>>>(h_ws, w1t, w3t, w2t, p_ws, out);
}

// Round 7
// 406.595 us; speedup vs baseline: 1.5068x; 1.0201x over previous
//
#include <hip/hip_runtime.h>
#include <hip/hip_bf16.h>
#include <cstdint>

#define B_SZ 8192
#define NH 16
#define HD 256
#define FH 512
#define BR 64            // batch rows per ffn block

typedef __bf16 bf16x8 __attribute__((ext_vector_type(8)));
typedef float f32x4 __attribute__((ext_vector_type(4)));

#define VMCNT(n) asm volatile("s_waitcnt vmcnt(" #n ")" ::: "memory")
#define LGKM0()  asm volatile("s_waitcnt lgkmcnt(0)" ::: "memory")
#define MEMFENCE() asm volatile("" ::: "memory")

// async global->LDS, 16 bytes per lane. lds base must be wave-uniform;
// lane i's data lands at lds_base + i*16.
__device__ __forceinline__ void lds_load16(const void* g, void* l) {
  __builtin_amdgcn_global_load_lds(
      (const __attribute__((address_space(1))) unsigned char*)g,
      (__attribute__((address_space(3))) unsigned char*)l, 16, 0, 0);
}

// ---------------- merged pre-pass (tests per-launch-overhead hypothesis):
//   blocks [0, 8192):      prep v3 (round-6 verbatim, coalesced, 1 barrier)
//   blocks [8192, 14336):  wcvt (round-1 verbatim): fp32 [NH][K][N] -> bf16 [NH][N][K]
// LDS manually overlaid: prep uses 16448 B (xs + rms1s), wcvt uses 4224 B (tile).
__global__ __launch_bounds__(256) void pre_kernel(const float* __restrict__ x,
                                                  const float* __restrict__ n1w,
                                                  const float* __restrict__ n2w,
                                                  const float* __restrict__ mask,
                                                  __bf16* __restrict__ p_ws,
                                                  __bf16* __restrict__ h_ws,
                                                  const float* __restrict__ w1,
                                                  const float* __restrict__ w3,
                                                  const float* __restrict__ w2,
                                                  __bf16* __restrict__ w1t,
                                                  __bf16* __restrict__ w3t,
                                                  __bf16* __restrict__ w2t) {
  __shared__ __attribute__((aligned(16))) char smem[16448];
  const int t = threadIdx.x;

  if (blockIdx.x < 8192) {
    // ================= prep v3: one block per batch row =================
    float4* xs = (float4*)smem;              // 16 KB swizzled row stash
    float* rms1s = (float*)(smem + 16384);   // 16 floats
    const int b = blockIdx.x;
    const int w = t >> 6;            // wave 0..3
    const int l = t & 63;            // lane

    const float4* xb4 = (const float4*)(x + (size_t)b * (NH * HD));

    // ---- phase 1: coalesced load + per-head sumsq (head of chunk q is w+4q)
    float4 xq[4];
    float ssq[4];
    #pragma unroll
    for (int q = 0; q < 4; ++q) {
      const int m = t + 256 * q;
      float4 v = xb4[m];
      xq[q] = v;
      ssq[q] = v.x * v.x + v.y * v.y + v.z * v.z + v.w * v.w;
      xs[m ^ ((m >> 6) & 7)] = v;    // swizzled stash for the transpose
    }
    #pragma unroll
    for (int d = 1; d < 64; d <<= 1) {
      #pragma unroll
      for (int q = 0; q < 4; ++q) ssq[q] += __shfl_xor(ssq[q], d);
    }
    if (l == 0) {
      #pragma unroll
      for (int q = 0; q < 4; ++q)
        rms1s[w + 4 * q] = rsqrtf(ssq[q] * (1.f / 256.f) + 1e-6f);
    }
    __syncthreads();                 // xs + rms1s published (only barrier)

    // ---- phase 2: transpose-read + mix + mask + residual; rms2 per head
    float4 pq[4];
    float ssq2[4];
    #pragma unroll
    for (int q = 0; q < 4; ++q) {
      const int m = t + 256 * q;
      const int i = m >> 6;
      const int c4 = m & 63;
      const int j = c4 >> 2;
      const int u = c4 & 3;
      const int src = j * 64 + i * 4 + u;          // src>>6 == j
      float4 sv = xs[src ^ (j & 7)];
      const float r1 = rms1s[j];
      float4 n1 = *(const float4*)(n1w + i * 16 + u * 4);
      float4 mk = *(const float4*)(mask + i * HD + j * 16 + u * 4);
      float4 p;
      p.x = sv.x * r1 * n1.x * mk.x + xq[q].x;
      p.y = sv.y * r1 * n1.y * mk.y + xq[q].y;
      p.z = sv.z * r1 * n1.z * mk.z + xq[q].z;
      p.w = sv.w * r1 * n1.w * mk.w + xq[q].w;
      pq[q] = p;
      ssq2[q] = p.x * p.x + p.y * p.y + p.z * p.z + p.w * p.w;
    }
    #pragma unroll
    for (int d = 1; d < 64; d <<= 1) {
      #pragma unroll
      for (int q = 0; q < 4; ++q) ssq2[q] += __shfl_xor(ssq2[q], d);
    }

    // ---- phase 3: pack + coalesced store
    #pragma unroll
    for (int q = 0; q < 4; ++q) {
      const int m = t + 256 * q;
      const int i = m >> 6;
      const int c4 = m & 63;
      const float r2 = rsqrtf(ssq2[q] * (1.f / 256.f) + 1e-6f);
      float4 n2 = *(const float4*)(n2w + c4 * 4);
      __bf16 pb[4] __attribute__((aligned(8)));
      __bf16 hv[4] __attribute__((aligned(8)));
      pb[0] = (__bf16)pq[q].x; hv[0] = (__bf16)(pq[q].x * r2 * n2.x);
      pb[1] = (__bf16)pq[q].y; hv[1] = (__bf16)(pq[q].y * r2 * n2.y);
      pb[2] = (__bf16)pq[q].z; hv[2] = (__bf16)(pq[q].z * r2 * n2.z);
      pb[3] = (__bf16)pq[q].w; hv[3] = (__bf16)(pq[q].w * r2 * n2.w);
      const size_t off = ((size_t)i * B_SZ + b) * HD + c4 * 4;
      *(uint2*)(p_ws + off) = *(uint2*)pb;
      *(uint2*)(h_ws + off) = *(uint2*)hv;
    }
    return;
  }

  // ================= wcvt =================
  float (*tile)[33] = (float(*)[33])smem;
  int bid = blockIdx.x - 8192;
  const float* src;
  __bf16* dst;
  int K, N;
  if (bid < 2048)      { src = w1; dst = w1t; K = 256; N = 512; }
  else if (bid < 4096) { src = w3; dst = w3t; K = 256; N = 512; bid -= 2048; }
  else                 { src = w2; dst = w2t; K = 512; N = 256; bid -= 4096; }
  const int tiles_n = N >> 5, tiles_k = K >> 5;
  const int per_head = tiles_n * tiles_k;
  const int head = bid / per_head;
  const int rem = bid - head * per_head;
  const int tk = rem / tiles_n;
  const int tn = rem - tk * tiles_n;
  const float* s = src + ((size_t)head * K + tk * 32) * N + tn * 32;
  const int r = t >> 3;             // 0..31
  const int c4 = (t & 7) * 4;       // 0..28
  float4 v = *(const float4*)(s + (size_t)r * N + c4);
  tile[r][c4 + 0] = v.x; tile[r][c4 + 1] = v.y;
  tile[r][c4 + 2] = v.z; tile[r][c4 + 3] = v.w;
  __syncthreads();
  __bf16 o[4] __attribute__((aligned(8)));
  #pragma unroll
  for (int j = 0; j < 4; ++j) o[j] = (__bf16)tile[c4 + j][r];
  __bf16* d = dst + ((size_t)head * N + tn * 32 + r) * K + tk * 32 + c4;
  *(uint2*)d = *(uint2*)o;
}

// ---------------- fused FFN (round-1 version, verbatim): counted-vmcnt ring.
// Per hc: 6 uniform stages of 4 global_load_lds/lane ping-pong across two
// 16KB Wbuf slots. All weight staging is wave-byte-private, so NO barriers
// guard Wbuf — only each wave's own s_waitcnt vmcnt(4). Cross-wave barriers:
// only the Sc publish and Sc WAR (2 raw s_barriers per hc).
__global__ __launch_bounds__(256, 2) void ffn_kernel(const __bf16* __restrict__ h_ws,
                                                     const __bf16* __restrict__ w1t,
                                                     const __bf16* __restrict__ w3t,
                                                     const __bf16* __restrict__ w2t,
                                                     const __bf16* __restrict__ p_ws,
                                                     float* __restrict__ out) {
  const int bid = blockIdx.x;
  const int head = bid & 15;            // head pinned to XCD bid%8 (2 heads/XCD)
  const int stripe = bid >> 4;          // 0..127
  const int r0 = stripe * BR;
  const int t = threadIdx.x;
  const int wv = t >> 6, lane = t & 63;
  const int mlane = lane & 15, quad = lane >> 4;

  __shared__ __bf16 __attribute__((aligned(16))) Hs[BR * HD];    // 32 KB [row][k], chunk c holds global c^(row&15)
  __shared__ __bf16 __attribute__((aligned(16))) Wbuf[16384];    // 32 KB = 2 slots x 16 KB (ring)
  __shared__ __bf16 __attribute__((aligned(16))) Sc[BR * 64];    //  8 KB [row][hid], chunk c holds global c^(row&7)

  const __bf16* W1h = w1t + (size_t)head * FH * HD;
  const __bf16* W3h = w3t + (size_t)head * FH * HD;
  const __bf16* W2h = w2t + (size_t)head * HD * FH;

  // ---- stage issue helpers (4 DMA loads/lane each; all wave-byte-private) ----
  auto stage1_issue = [&](__bf16* Ws, int hc, int kk) {
    const int rl = lane >> 3, c = lane & 7, gch = c ^ rl;
    #pragma unroll
    for (int i = 0; i < 2; ++i) {
      const int rb = wv * 16 + i * 8;
      const size_t go = (size_t)(hc * 64 + rb + rl) * HD + kk * 64 + gch * 8;
      lds_load16(W1h + go, Ws + rb * 64);
      lds_load16(W3h + go, Ws + 4096 + rb * 64);
    }
  };
  auto stage2_issue = [&](__bf16* Ws, int hc, int ks) {
    const int rl = lane >> 2, c = lane & 3, gch = c ^ (rl & 3);
    #pragma unroll
    for (int i = 0; i < 4; ++i) {
      const int rb = wv * 64 + i * 16;
      lds_load16(W2h + (size_t)(rb + rl) * FH + hc * 64 + ks * 32 + gch * 8,
                 Ws + (i >> 1) * 4096 + wv * 1024 + (i & 1) * 512);
    }
  };

  // ---- prologue: stage Hs (8 loads/wave), then prefetch s1k0/s1k1 of hc=0
  const __bf16* Hb = h_ws + ((size_t)head * B_SZ + r0) * HD;
  {
    const int rloc = lane >> 5;       // 0/1
    const int ch = lane & 31;
    #pragma unroll
    for (int i = 0; i < 8; ++i) {
      const int row = wv * 16 + i * 2 + rloc;
      const int gch = ch ^ (row & 15);
      lds_load16(Hb + (size_t)row * HD + gch * 8, Hs + (wv * 16 + i * 2) * HD);
    }
  }
  MEMFENCE();                       // keep Hs DMAs ordered before prefetches
  stage1_issue(Wbuf, 0, 0);
  stage1_issue(Wbuf + 8192, 0, 1);
  VMCNT(8);                         // own 8 Hs loads done (8 prefetches in flight)
  __builtin_amdgcn_s_barrier();     // Hs visible to all waves (read-only after)

  f32x4 oacc[4][4];
  #pragma unroll
  for (int mt = 0; mt < 4; ++mt)
    #pragma unroll
    for (int nt = 0; nt < 4; ++nt) oacc[mt][nt] = (f32x4){0.f, 0.f, 0.f, 0.f};

  for (int hc = 0; hc < 8; ++hc) {
    // ================= stage 1: g/v[64 hid chunk][64 rows], K=256 =================
    f32x4 g[4], v[4];
    #pragma unroll
    for (int nt = 0; nt < 4; ++nt) {
      g[nt] = (f32x4){0.f, 0.f, 0.f, 0.f};
      v[nt] = (f32x4){0.f, 0.f, 0.f, 0.f};
    }
    #pragma unroll
    for (int kk = 0; kk < 4; ++kk) {
      __bf16* Ws = Wbuf + (kk & 1) * 8192;
      VMCNT(4);                     // own slot loads done; next stage in flight
      #pragma unroll
      for (int ks = 0; ks < 2; ++ks) {
        const int ar = wv * 16 + mlane;            // wave-private hid row
        const int ach = (ks * 4 + quad) ^ (ar & 7);
        bf16x8 a1 = *(const bf16x8*)(Ws + ar * 64 + ach * 8);
        bf16x8 a3 = *(const bf16x8*)(Ws + 4096 + ar * 64 + ach * 8);
        const int gk = kk * 8 + ks * 4 + quad;     // global 8-elem k-chunk
        bf16x8 b[4];
        #pragma unroll
        for (int nt = 0; nt < 4; ++nt) {
          const int row = nt * 16 + mlane;
          b[nt] = *(const bf16x8*)(Hs + row * HD + (gk ^ (row & 15)) * 8);
        }
        if (ks == 1) {
          LGKM0();                  // this wave's slot reads retired -> safe to overwrite
          if (kk < 2) stage1_issue(Ws, hc, kk + 2);
          else        stage2_issue(Ws, hc, kk - 2);
        }
        __builtin_amdgcn_s_setprio(1);
        #pragma unroll
        for (int nt = 0; nt < 4; ++nt) {
          g[nt] = __builtin_amdgcn_mfma_f32_16x16x32_bf16(a1, b[nt], g[nt], 0, 0, 0);
          v[nt] = __builtin_amdgcn_mfma_f32_16x16x32_bf16(a3, b[nt], v[nt], 0, 0, 0);
        }
        __builtin_amdgcn_s_setprio(0);
      }
    }

    // ---- silu -> Sc
    #pragma unroll
    for (int nt = 0; nt < 4; ++nt) {
      const int row = nt * 16 + mlane;
      __bf16 sv[4] __attribute__((aligned(8)));
      #pragma unroll
      for (int r = 0; r < 4; ++r) {
        const float gg = g[nt][r];
        sv[r] = (__bf16)(gg / (1.f + __expf(-gg)) * v[nt][r]);
      }
      const int boff = wv * 32 + quad * 8;          // byte offset of hid-local in row
      const int ph = ((boff >> 4) ^ (row & 7));
      char* dst = (char*)Sc + row * 128 + ph * 16 + (boff & 15);
      *(uint2*)dst = *(uint2*)sv;
    }
    LGKM0();
    __builtin_amdgcn_s_barrier();   // BARRIER_A: Sc published (counted vmcnt untouched)

    // ================= stage 2: oacc += W2[:, hc*64..+64] * Sc =================
    const int hcn = (hc + 1) & 7;   // hc=7 issues dummy hc=0 prefetches (keeps vmcnt math uniform)
    #pragma unroll
    for (int ks = 0; ks < 2; ++ks) {
      __bf16* Ws = Wbuf + (ks & 1) * 8192;
      VMCNT(4);                     // own W2 chunk done; other stage in flight
      bf16x8 a2[4], b2[4];
      #pragma unroll
      for (int mt = 0; mt < 4; ++mt)
        a2[mt] = *(const bf16x8*)(Ws + (mt >> 1) * 4096 + wv * 1024 + (mt & 1) * 512
                                  + mlane * 32 + ((quad ^ (mlane & 3))) * 8);
      #pragma unroll
      for (int nt = 0; nt < 4; ++nt) {
        const int row = nt * 16 + mlane;
        b2[nt] = *(const bf16x8*)(Sc + row * 64 + (((ks * 4 + quad) ^ (row & 7))) * 8);
      }
      LGKM0();                      // Sc + slot reads retired
      stage1_issue(Ws, hcn, ks);    // prefetch next hc's s1k0/s1k1
      if (ks == 1) __builtin_amdgcn_s_barrier();  // BARRIER_B: Sc WAR before next silu
      __builtin_amdgcn_s_setprio(1);
      #pragma unroll
      for (int mt = 0; mt < 4; ++mt)
        #pragma unroll
        for (int nt = 0; nt < 4; ++nt)
          oacc[mt][nt] = __builtin_amdgcn_mfma_f32_16x16x32_bf16(a2[mt], b2[nt], oacc[mt][nt], 0, 0, 0);
      __builtin_amdgcn_s_setprio(0);
    }
  }

  VMCNT(0);   // drain dummy prefetches: no DMA may outlive this block's LDS

  // ---- epilogue: out[b][head*256+oc] = oacc + p
  const __bf16* Pb = p_ws + ((size_t)head * B_SZ + r0) * HD;
  float* Ob = out + (size_t)r0 * (NH * HD) + head * HD;
  #pragma unroll
  for (int mt = 0; mt < 4; ++mt)
    #pragma unroll
    for (int nt = 0; nt < 4; ++nt) {
      const int row = nt * 16 + mlane;
      const int oc = wv * 64 + mt * 16 + quad * 4;
      __bf16 pv[4] __attribute__((aligned(8)));
      *(uint2*)pv = *(const uint2*)(Pb + (size_t)row * HD + oc);
      float4 o;
      o.x = oacc[mt][nt][0] + (float)pv[0];
      o.y = oacc[mt][nt][1] + (float)pv[1];
      o.z = oacc[mt][nt][2] + (float)pv[2];
      o.w = oacc[mt][nt][3] + (float)pv[3];
      *(float4*)(Ob + (size_t)row * (NH * HD) + oc) = o;
    }
}

extern "C" void kernel_launch(void* const* d_in, const int* in_sizes, int n_in,
                              void* d_out, int out_size, void* d_ws, size_t ws_size,
                              hipStream_t stream) {
  const float* x    = (const float*)d_in[0];
  const float* n1w  = (const float*)d_in[1];
  const float* n2w  = (const float*)d_in[2];
  const float* w1   = (const float*)d_in[3];
  const float* w3   = (const float*)d_in[4];
  const float* w2   = (const float*)d_in[5];
  const float* mask = (const float*)d_in[6];
  float* out = (float*)d_out;

  char* ws = (char*)d_ws;
  // ws layout (bytes):
  //   p_ws  bf16 [16][8192][256]  @ 0          (67108864)
  //   h_ws  bf16 [16][8192][256]  @ 67108864   (67108864)
  //   w1t   bf16 [16][512][256]   @ 134217728  ( 4194304)
  //   w3t   bf16 [16][512][256]   @ 138412032  ( 4194304)
  //   w2t   bf16 [16][256][512]   @ 142606336  ( 4194304)
  __bf16* p_ws = (__bf16*)(ws + 0);
  __bf16* h_ws = (__bf16*)(ws + 67108864);
  __bf16* w1t  = (__bf16*)(ws + 134217728);
  __bf16* w3t  = (__bf16*)(ws + 138412032);
  __bf16* w2t  = (__bf16*)(ws + 142606336);

  pre_kernel<<<14336, 256, 0, stream>>>(x, n1w, n2w, mask, p_ws, h_ws,
                                        w1, w3, w2, w1t, w3t, w2t);
  ffn_kernel<<<2048, 256, 0, stream>>>(h_ws, w1t, w3t, w2t, p_ws, out);
}